// Round 1
// baseline (1706.070 us; speedup 1.0000x reference)
//
#include <hip/hip_runtime.h>
#include <hip/hip_bf16.h>

// GCN: out = (elu(gc(elu(gc(elu(z*),W0,b0)),W1,b1)) concat) @ Wl^T + bl
// gc(x,W,b) = adj @ (x @ W) + b ; adj is 16384^2 fp32 (1 GiB).
// Strategy: bf16 MFMA for the two adj@T products (tolerance is ~2% of max|ref|),
// adj converted fp32->bf16 in-register during LDS staging (reads adj fp32 once
// per layer: 2 GiB HBM floor ~= 325 us @ 6.3 TB/s). T operands stored
// column-major bf16 so B-fragments are contiguous-in-K for ds_read_b128.

#define NN 16384
#define C2 128   // 2*D_IN
#define DIN 64
#define DOUT 32

typedef __attribute__((ext_vector_type(8))) __bf16 bf16x8;
typedef __attribute__((ext_vector_type(4))) float f32x4;

__device__ __forceinline__ float eluf(float x) {
    return x > 0.f ? x : __expf(x) - 1.f;
}

__device__ __forceinline__ unsigned short f2bf(float f) {
    unsigned u = __float_as_uint(f);
    u += 0x7FFFu + ((u >> 16) & 1u);   // RNE
    return (unsigned short)(u >> 16);
}

// ---------------------------------------------------------------------------
// small_mm: T[c*NN + r] = sum_k ELU?(X[r, (c>>6)*64 + k]) * W[k, c&63]  (bf16 out, col-major)
// X: NN x 128 row-major fp32. W: 64x64 row-major fp32.
// block: 256 threads = 64 rows x 2 input-halves x 2 col-quarters; grid: NN/64
template <bool ELU_IN>
__global__ __launch_bounds__(256)
void small_mm(const float* __restrict__ X, const float* __restrict__ W,
              unsigned short* __restrict__ Tcm)
{
    __shared__ float WsT[DIN * DIN];   // [c][k] transposed: WsT[c*64+k] = W[k*64+c]
    const int tid = threadIdx.x;
    for (int i = tid; i < DIN * DIN; i += 256) {
        int c = i >> 6, k = i & 63;
        WsT[i] = W[k * DIN + c];
    }
    __syncthreads();

    const int r     = tid & 63;
    const int chalf = (tid >> 6) & 1;
    const int cq    = tid >> 7;           // 0..1 -> 32 output cols each
    const size_t row = (size_t)blockIdx.x * 64 + r;

    float e[DIN];
    const float* xp = X + row * C2 + chalf * DIN;
#pragma unroll
    for (int i = 0; i < 16; i++) {
        float4 v = ((const float4*)xp)[i];
        if (ELU_IN) { v.x = eluf(v.x); v.y = eluf(v.y); v.z = eluf(v.z); v.w = eluf(v.w); }
        e[i*4+0] = v.x; e[i*4+1] = v.y; e[i*4+2] = v.z; e[i*4+3] = v.w;
    }

    for (int j = 0; j < 32; j++) {
        int cc = cq * 32 + j;
        const float* wr = WsT + cc * DIN;
        float a = 0.f;
#pragma unroll
        for (int k = 0; k < DIN; k += 4) {
            float4 w = *(const float4*)(wr + k);
            a += e[k]*w.x + e[k+1]*w.y + e[k+2]*w.z + e[k+3]*w.w;
        }
        int c = (chalf << 6) + cc;
        Tcm[(size_t)c * NN + row] = f2bf(a);
    }
}

// ---------------------------------------------------------------------------
// big_gemm: Y[r,c] = elu( sum_k A[r,k]*T[k,c] + bias[c&63] ), A fp32 NNxNN, T bf16 col-major
// tile 32 rows x 128 cols, BK=128, 256 threads (4 waves: wave w owns cols 32w..32w+31)
__global__ __launch_bounds__(256, 2)
void big_gemm(const float* __restrict__ A, const unsigned short* __restrict__ Bcm,
              const float* __restrict__ bias, float* __restrict__ Y)
{
    __shared__ unsigned short As[32 * 136];    // [r][k] pad 136 (2-way alias = free)
    __shared__ unsigned short Bs[128 * 136];   // [c][k] pad 136

    const int tid  = threadIdx.x;
    const int lane = tid & 63;
    const int wave = tid >> 6;
    const int m    = lane & 15;
    const int kq   = lane >> 4;
    const size_t row0 = (size_t)blockIdx.x * 32;

    f32x4 acc[2][2];
#pragma unroll
    for (int i = 0; i < 2; i++)
#pragma unroll
        for (int j = 0; j < 2; j++) acc[i][j] = (f32x4){0.f, 0.f, 0.f, 0.f};

    for (int k0 = 0; k0 < NN; k0 += 128) {
        __syncthreads();
        // stage A tile 32x128 fp32 -> bf16 LDS (16 KiB global / iter / WG)
#pragma unroll
        for (int i = 0; i < 4; i++) {
            int id = tid + i * 256;
            int r  = id >> 5;            // 0..31
            int kk = (id & 31) * 4;      // 0..124
            float4 v = *(const float4*)(A + (row0 + r) * (size_t)NN + k0 + kk);
            unsigned lo = f2bf(v.x) | ((unsigned)f2bf(v.y) << 16);
            unsigned hi = f2bf(v.z) | ((unsigned)f2bf(v.w) << 16);
            *(uint2*)(&As[r * 136 + kk]) = make_uint2(lo, hi);
        }
        // stage B tile 128(k) x 128(c): col-major source -> Bs[c][k] contiguous in k
#pragma unroll
        for (int i = 0; i < 8; i++) {
            int id = tid + i * 256;
            int c  = id >> 4;            // 0..127
            int kk = (id & 15) * 8;      // 0..120
            float4 v = *(const float4*)(Bcm + (size_t)c * NN + k0 + kk);
            *(float4*)(&Bs[c * 136 + kk]) = v;
        }
        __syncthreads();
#pragma unroll
        for (int s = 0; s < 4; s++) {
            bf16x8 a0 = *(const bf16x8*)(&As[ m       * 136 + s * 32 + kq * 8]);
            bf16x8 a1 = *(const bf16x8*)(&As[(16 + m) * 136 + s * 32 + kq * 8]);
            bf16x8 b0 = *(const bf16x8*)(&Bs[(wave * 32 + m     ) * 136 + s * 32 + kq * 8]);
            bf16x8 b1 = *(const bf16x8*)(&Bs[(wave * 32 + 16 + m) * 136 + s * 32 + kq * 8]);
            acc[0][0] = __builtin_amdgcn_mfma_f32_16x16x32_bf16(a0, b0, acc[0][0], 0, 0, 0);
            acc[1][0] = __builtin_amdgcn_mfma_f32_16x16x32_bf16(a1, b0, acc[1][0], 0, 0, 0);
            acc[0][1] = __builtin_amdgcn_mfma_f32_16x16x32_bf16(a0, b1, acc[0][1], 0, 0, 0);
            acc[1][1] = __builtin_amdgcn_mfma_f32_16x16x32_bf16(a1, b1, acc[1][1], 0, 0, 0);
        }
    }

    // epilogue: C/D layout col=lane&15, row=(lane>>4)*4+reg
#pragma unroll
    for (int mt = 0; mt < 2; mt++)
#pragma unroll
        for (int nt = 0; nt < 2; nt++) {
            int cc = wave * 32 + nt * 16 + m;
            float b = bias[cc & 63];
#pragma unroll
            for (int reg = 0; reg < 4; reg++) {
                size_t rr = row0 + mt * 16 + kq * 4 + reg;
                float v = acc[mt][nt][reg] + b;
                v = v > 0.f ? v : __expf(v) - 1.f;
                Y[rr * C2 + cc] = v;
            }
        }
}

// ---------------------------------------------------------------------------
// final_mm: out[r,o] = sum_c Y[r,c]*Wl[o,c] + bl[o]
// block: 256 threads = 64 rows x 4 c-quarters; LDS tree-reduce over quarters
__global__ __launch_bounds__(256)
void final_mm(const float* __restrict__ Y, const float* __restrict__ Wl,
              const float* __restrict__ bl, float* __restrict__ out)
{
    __shared__ float WlT[C2 * DOUT];     // [c][o]
    __shared__ float red[4 * 64 * 33];   // [cq][r][o] pad 33
    const int tid = threadIdx.x;
    for (int i = tid; i < C2 * DOUT; i += 256) {
        int c = i >> 5, o = i & 31;
        WlT[i] = Wl[o * C2 + c];
    }
    __syncthreads();

    const int r  = tid & 63;
    const int cq = tid >> 6;
    const size_t row = (size_t)blockIdx.x * 64 + r;

    float acc[DOUT];
#pragma unroll
    for (int o = 0; o < DOUT; o++) acc[o] = 0.f;

    const float* yp = Y + row * C2 + cq * 32;
#pragma unroll
    for (int i = 0; i < 8; i++) {
        float4 y = ((const float4*)yp)[i];
        int cb = cq * 32 + i * 4;
#pragma unroll
        for (int o4 = 0; o4 < 8; o4++) {
            float4 w0 = *(const float4*)(WlT + (cb + 0) * DOUT + o4 * 4);
            float4 w1 = *(const float4*)(WlT + (cb + 1) * DOUT + o4 * 4);
            float4 w2 = *(const float4*)(WlT + (cb + 2) * DOUT + o4 * 4);
            float4 w3 = *(const float4*)(WlT + (cb + 3) * DOUT + o4 * 4);
            acc[o4*4+0] += y.x*w0.x + y.y*w1.x + y.z*w2.x + y.w*w3.x;
            acc[o4*4+1] += y.x*w0.y + y.y*w1.y + y.z*w2.y + y.w*w3.y;
            acc[o4*4+2] += y.x*w0.z + y.y*w1.z + y.z*w2.z + y.w*w3.z;
            acc[o4*4+3] += y.x*w0.w + y.y*w1.w + y.z*w2.w + y.w*w3.w;
        }
    }

    float* myred = red + (cq * 64 + r) * 33;
#pragma unroll
    for (int o = 0; o < DOUT; o++) myred[o] = acc[o];
    __syncthreads();

#pragma unroll
    for (int j = 0; j < 8; j++) {
        int id = tid + 256 * j;
        int o  = id & 31;
        int rr = id >> 5;
        float s = bl[o] + red[(0 * 64 + rr) * 33 + o] + red[(1 * 64 + rr) * 33 + o]
                        + red[(2 * 64 + rr) * 33 + o] + red[(3 * 64 + rr) * 33 + o];
        out[((size_t)blockIdx.x * 64 + rr) * DOUT + o] = s;
    }
}

// ---------------------------------------------------------------------------
extern "C" void kernel_launch(void* const* d_in, const int* in_sizes, int n_in,
                              void* d_out, int out_size, void* d_ws, size_t ws_size,
                              hipStream_t stream)
{
    const float* z   = (const float*)d_in[0];
    const float* adj = (const float*)d_in[1];
    const float* W0  = (const float*)d_in[2];
    const float* b0  = (const float*)d_in[3];
    const float* W1  = (const float*)d_in[4];
    const float* b1  = (const float*)d_in[5];
    const float* Wl  = (const float*)d_in[6];
    const float* bl  = (const float*)d_in[7];
    float* out = (float*)d_out;

    // workspace: T (bf16 col-major 128 x NN = 4 MiB) + Y (fp32 NN x 128 = 8 MiB)
    unsigned short* T = (unsigned short*)d_ws;
    float* Y = (float*)((char*)d_ws + (size_t)C2 * NN * sizeof(unsigned short));

    small_mm<true ><<<NN / 64, 256, 0, stream>>>(z, W0, T);   // T0 = elu(z) @ W0 (both halves)
    big_gemm      <<<NN / 32, 256, 0, stream>>>(adj, T, b0, Y); // Y1 = elu(adj@T0 + b0)
    small_mm<false><<<NN / 64, 256, 0, stream>>>(Y, W1, T);   // T1 = Y1 @ W1
    big_gemm      <<<NN / 32, 256, 0, stream>>>(adj, T, b1, Y); // Y2 = elu(adj@T1 + b1)
    final_mm      <<<NN / 64, 256, 0, stream>>>(Y, Wl, bl, out); // out = Y2 @ Wl^T + bl
}